// Round 8
// baseline (199.477 us; speedup 1.0000x reference)
//
#include <hip/hip_runtime.h>

#define BB    4096
#define NNUM  64
#define NCAT  64
#define CARD  100
#define DD    512
#define FF    128

// workspace layout (9.44 MB — proven to fit)
#define WS_POOLED_BYTES ((size_t)BB * DD * 4)            // 8 MB
#define WS_CNT_OFF      WS_POOLED_BYTES
#define WS_LIST_OFF     (WS_CNT_OFF + 256)
#define WS_NEEDED       (WS_LIST_OFF + (size_t)64 * BB * 4)

// ---------------- kernel Pool v8: row-per-fg, lockstep feature walk ----
// 1025 blocks x 512 threads. Block 0 = expert sorter. Blocks 1..1024 own rows
// [(blk-1)*4, +4). fg = tid>>7 owns ROW fg (all 64 features); tl = tid&127
// owns d4 = tl*4.
// KEY IDEA: every fg in every block walks features 0..63 in the SAME order.
// The whole grid (1024 blocks = 4/CU, fully co-resident) advances through
// emb_cat in lockstep -> instantaneous table slice ~ few features x 200 KB
// << 4 MiB XCD-L2 -> gathers hit L2 instead of L3. Also: no cross-fg tree
// reduction (acc = 8 regs), LDS 39 -> 15 KB.
// REGISTER RULES (measured): launch_bounds 2nd arg = min BLOCKS/CU; (512,4)
// -> hard 64-VGPR cap (R5). VGPR occupancy steps at 64/128/256: >64 regs
// halves waves/SIMD (R7: 72 regs -> occupancy 36->21%, FETCH +25 MB). Stay <=64.
__global__ __launch_bounds__(512, 4) void pool_kernel(
    const float* __restrict__ x_num, const int* __restrict__ x_cat,
    const float* __restrict__ mask_num, const float* __restrict__ mask_cat,
    const int* __restrict__ pred_idx_num, const int* __restrict__ pred_idx_cat,
    const float* __restrict__ w_num, const float* __restrict__ b_num,
    const float* __restrict__ emb_cat, const float* __restrict__ b_cat,
    const float* __restrict__ dec_num_W, const float* __restrict__ dec_num_b,
    int* __restrict__ cnt, int* __restrict__ list,
    float* __restrict__ pooled_cat,   // ws (B,512)
    float* __restrict__ out)          // out[0..B) = pred_num
{
    const int blk = blockIdx.x;
    const int tid = threadIdx.x;

    __shared__ float s_mn[4][FF];          // 2 KB
    __shared__ float s_mc[4][FF];          // 2 KB
    __shared__ float s_x[4][NNUM];         // 1 KB
    __shared__ int   s_idx[4][NCAT];       // 1 KB
    __shared__ float s_msum[2][4];
    __shared__ float s_pn[4][DD];          // 8 KB (pooled_num staging)

    // ---- block 0: expert counting-scatter (replaces memset + atomic binning) ----
    if (blk == 0) {
        int* s_hist = (int*)&s_mn[0][0];   // reuse LDS
        if (tid < 64) s_hist[tid] = 0;
        __syncthreads();
        for (int i = tid; i < BB; i += 512) {
            const int e = pred_idx_cat[i] - NNUM;
            const int pos = atomicAdd(&s_hist[e], 1);   // LDS atomic
            list[e * BB + pos] = i;
        }
        __syncthreads();
        if (tid < 64) cnt[tid] = s_hist[tid];
        return;
    }

    const int tl  = tid & 127;
    const int fg  = tid >> 7;          // row 0..3 within block
    const int d4  = tl * 4;
    const int rowbase = (blk - 1) * 4;

    // ---- stage row data (perfectly coalesced) ----
    ((float*)s_mn)[tid] = mask_num[rowbase * FF + tid];
    ((float*)s_mc)[tid] = mask_cat[rowbase * FF + tid];
    if (tid < 256) ((float*)s_x)[tid]       = x_num[rowbase * NNUM + tid];
    else           ((int*)s_idx)[tid - 256] = x_cat[rowbase * NCAT + (tid - 256)];
    __syncthreads();

    // mask sums (8 threads; consumed after the next barrier)
    if (tid < 8) {
        const int r  = tid >> 1;
        const int ty = tid & 1;
        const float* m = ty ? s_mc[r] : s_mn[r];
        float s = 0.f;
        #pragma unroll 8
        for (int f2 = 0; f2 < FF; ++f2) s += m[f2];
        s_msum[ty][r] = s;
    }

    float accN[4] = {0.f, 0.f, 0.f, 0.f};
    float accC[4] = {0.f, 0.f, 0.f, 0.f};

    const float* __restrict__ mnr = s_mn[fg];
    const float* __restrict__ mcr = s_mc[fg];
    const float* __restrict__ xr  = s_x[fg];
    const int*   __restrict__ ixr = s_idx[fg];

    // ---- lockstep feature walk: numeric f + categorical f per iteration ----
    #pragma unroll 4
    for (int f = 0; f < 64; ++f) {
        // categorical gather for this row (wave-uniform skip when dead)
        const float mnc = mnr[NNUM + f];
        const float mcc = mcr[NNUM + f];
        float4 ev = make_float4(0.f, 0.f, 0.f, 0.f);
        if (mnc != 0.f || mcc != 0.f) {
            ev = *(const float4*)(emb_cat + (size_t)(f * CARD + ixr[f]) * DD + d4);
        }
        const float4 bc = *(const float4*)(b_cat + f * DD + d4);

        // numeric feature f (dense tensors: 128 KB each, L2-resident)
        const float4 w  = *(const float4*)(w_num + f * DD + d4);
        const float4 bb = *(const float4*)(b_num + f * DD + d4);
        const float mn = mnr[f];
        const float mc = mcr[f];
        const float x  = xr[f];
        {
            const float tx = fmaf(x, w.x, bb.x);
            const float ty = fmaf(x, w.y, bb.y);
            const float tz = fmaf(x, w.z, bb.z);
            const float tw = fmaf(x, w.w, bb.w);
            accN[0] = fmaf(mn, tx, accN[0]); accN[1] = fmaf(mn, ty, accN[1]);
            accN[2] = fmaf(mn, tz, accN[2]); accN[3] = fmaf(mn, tw, accN[3]);
            accC[0] = fmaf(mc, tx, accC[0]); accC[1] = fmaf(mc, ty, accC[1]);
            accC[2] = fmaf(mc, tz, accC[2]); accC[3] = fmaf(mc, tw, accC[3]);
        }
        // consume categorical gather
        {
            const float tx = ev.x + bc.x;
            const float ty = ev.y + bc.y;
            const float tz = ev.z + bc.z;
            const float tw = ev.w + bc.w;
            accN[0] = fmaf(mnc, tx, accN[0]); accN[1] = fmaf(mnc, ty, accN[1]);
            accN[2] = fmaf(mnc, tz, accN[2]); accN[3] = fmaf(mnc, tw, accN[3]);
            accC[0] = fmaf(mcc, tx, accC[0]); accC[1] = fmaf(mcc, ty, accC[1]);
            accC[2] = fmaf(mcc, tz, accC[2]); accC[3] = fmaf(mcc, tw, accC[3]);
        }
    }

    __syncthreads();   // s_msum visible

    // ---- finalize: each fg writes its own row (no tree reduction needed) ----
    {
        const float invN = 1.f / s_msum[0][fg];
        const float invC = 1.f / s_msum[1][fg];
        const int row = rowbase + fg;
        float4 pc;
        pc.x = accC[0] * invC; pc.y = accC[1] * invC;
        pc.z = accC[2] * invC; pc.w = accC[3] * invC;
        *(float4*)(pooled_cat + (size_t)row * DD + d4) = pc;
        float4 pn;
        pn.x = accN[0] * invN; pn.y = accN[1] * invN;
        pn.z = accN[2] * invN; pn.w = accN[3] * invN;
        *(float4*)(&s_pn[fg][d4]) = pn;
    }
    __syncthreads();

    // ---- numeric head: waves 0..3 handle rows 0..3 ----
    const int wv   = tid >> 6;
    const int lane = tid & 63;
    if (wv < 4) {
        const int row = rowbase + wv;
        const int idx = pred_idx_num[row];
        const float* W = dec_num_W + (size_t)idx * DD + lane * 8;
        const float4 a0 = *(const float4*)(W);
        const float4 a1 = *(const float4*)(W + 4);
        const float4 p0 = *(const float4*)(&s_pn[wv][lane * 8]);
        const float4 p1 = *(const float4*)(&s_pn[wv][lane * 8 + 4]);
        float v = a0.x * p0.x + a0.y * p0.y + a0.z * p0.z + a0.w * p0.w
                + a1.x * p1.x + a1.y * p1.y + a1.z * p1.z + a1.w * p1.w;
        #pragma unroll
        for (int off = 32; off > 0; off >>= 1) v += __shfl_down(v, off);
        if (lane == 0) out[row] = v + dec_num_b[idx];
    }
}

// ---------------- kernel CatHead v3 (R3-proven): 32-row tiles, 256 threads ----
// grid (64 experts, 2 col-halves, 4 row-tile phases) x 256 threads.
// Each block: 32 rows x 50 cols, K=512 accumulated across 4 k-chunks in
// registers -> no atomics; bias fused into the store.
__global__ __launch_bounds__(256) void cat_head(
    const float* __restrict__ pooled_cat,
    const int* __restrict__ cnt, const int* __restrict__ list,
    const float* __restrict__ dec_cat_W, const float* __restrict__ dec_cat_b,
    float* __restrict__ out)
{
    const int e   = blockIdx.x;
    const int ch  = blockIdx.y;      // 0..1 (column half: 50 cards each)
    const int t   = blockIdx.z;      // 0..3 (row-tile phase, 32 rows each)
    const int tid = threadIdx.x;

    const int n = cnt[e];
    if (t * 32 >= n) return;         // empty tile -> exit (uniform)

    __shared__ float sW[8512];       // 50 cards x 128k, swizzled (34 KB)
    __shared__ float sP[32 * 132];   // 16.9 KB
    __shared__ int   s_rows[32];

    const int rg = tid >> 4;         // 0..15: 2 rows each
    const int cg = tid & 15;         // 0..15: 4 cols each (cl<50 valid)

    // per-thread column biases (uniform per block; loaded once)
    float bias[4];
    #pragma unroll
    for (int bq = 0; bq < 4; ++bq) {
        const int cl = cg * 4 + bq;
        bias[bq] = (cl < 50) ? dec_cat_b[e * CARD + ch * 50 + cl] : 0.f;
    }

    for (int rbase = t * 32; rbase < n; rbase += 128) {
        if (tid < 32) {
            const int ri = rbase + tid;
            s_rows[tid] = (ri < n) ? list[e * BB + ri] : -1;
        }

        float acc[2][4];
        #pragma unroll
        for (int a = 0; a < 2; ++a)
            #pragma unroll
            for (int bq = 0; bq < 4; ++bq) acc[a][bq] = 0.f;

        for (int dq = 0; dq < 4; ++dq) {
            __syncthreads();   // s_rows visible (dq==0) / prev compute done (dq>0)

            // stage W chunk: 50 cards x 128 k (swizzled to dodge bank conflicts)
            const float* Wb = dec_cat_W + ((size_t)e * CARD + ch * 50) * DD + dq * 128;
            for (int idx = tid; idx < 50 * 32; idx += 256) {
                const int c = idx >> 5;
                const int j = idx & 31;
                const float4 v = *(const float4*)(Wb + (size_t)c * DD + j * 4);
                *(float4*)(sW + c * 132 + (c >> 2) * 4 + j * 4) = v;
            }
            // stage P chunk: 32 rows x 128 k
            for (int idx = tid; idx < 32 * 32; idx += 256) {
                const int rl = idx >> 5;
                const int j  = idx & 31;
                const int row = s_rows[rl];
                float4 v = make_float4(0.f, 0.f, 0.f, 0.f);
                if (row >= 0)
                    v = *(const float4*)(pooled_cat + (size_t)row * DD + dq * 128 + j * 4);
                *(float4*)(sP + rl * 132 + j * 4) = v;
            }
            __syncthreads();

            #pragma unroll 4
            for (int k = 0; k < 32; ++k) {
                float4 p[2], w[4];
                #pragma unroll
                for (int a = 0; a < 2; ++a)
                    p[a] = *(const float4*)(sP + (rg * 2 + a) * 132 + k * 4);
                #pragma unroll
                for (int bq = 0; bq < 4; ++bq) {
                    const int cl = cg * 4 + bq;
                    w[bq] = *(const float4*)(sW + cl * 132 + (cl >> 2) * 4 + k * 4);
                }
                #pragma unroll
                for (int a = 0; a < 2; ++a)
                    #pragma unroll
                    for (int bq = 0; bq < 4; ++bq) {
                        acc[a][bq] = fmaf(p[a].x, w[bq].x, acc[a][bq]);
                        acc[a][bq] = fmaf(p[a].y, w[bq].y, acc[a][bq]);
                        acc[a][bq] = fmaf(p[a].z, w[bq].z, acc[a][bq]);
                        acc[a][bq] = fmaf(p[a].w, w[bq].w, acc[a][bq]);
                    }
            }
        }

        // direct store with fused bias (each output element owned by one thread)
        #pragma unroll
        for (int a = 0; a < 2; ++a) {
            const int row = s_rows[rg * 2 + a];
            if (row >= 0) {
                float* orow = out + BB + (size_t)row * CARD + ch * 50;
                #pragma unroll
                for (int bq = 0; bq < 4; ++bq) {
                    const int cl = cg * 4 + bq;
                    if (cl < 50) orow[cl] = acc[a][bq] + bias[bq];
                }
            }
        }
        __syncthreads();   // stores read s_rows; next iter overwrites it
    }
}

// ---------------- fallback: monolithic (used only if ws too small) ----------------
__global__ __launch_bounds__(128) void rtdl_fused(
    const float* __restrict__ x_num, const int* __restrict__ x_cat,
    const float* __restrict__ mask_num, const float* __restrict__ mask_cat,
    const int* __restrict__ pred_idx_num, const int* __restrict__ pred_idx_cat,
    const float* __restrict__ w_num, const float* __restrict__ b_num,
    const float* __restrict__ emb_cat, const float* __restrict__ b_cat,
    const float* __restrict__ dec_num_W, const float* __restrict__ dec_num_b,
    const float* __restrict__ dec_cat_W, const float* __restrict__ dec_cat_b,
    float* __restrict__ out)
{
    const int b   = blockIdx.x;
    const int tid = threadIdx.x;
    __shared__ float s_mn[FF];
    __shared__ float s_mc[FF];
    __shared__ float s_xn[NNUM];
    __shared__ int   s_xc[NCAT];
    __shared__ float s_pn[DD];
    __shared__ float s_pc[DD];
    s_mn[tid] = mask_num[b * FF + tid];
    s_mc[tid] = mask_cat[b * FF + tid];
    if (tid < NNUM) { s_xn[tid] = x_num[b * NNUM + tid]; s_xc[tid] = x_cat[b * NCAT + tid]; }
    __syncthreads();
    float sn = 0.f, sc = 0.f;
    for (int f = 0; f < FF; ++f) { sn += s_mn[f]; sc += s_mc[f]; }
    const float inv_n = 1.f / sn, inv_c = 1.f / sc;
    const int d4 = tid * 4;
    float anx=0,any_=0,anz=0,anw=0,acx=0,acy=0,acz=0,acw=0;
    for (int f = 0; f < NNUM; ++f) {
        const float mn = s_mn[f], mc = s_mc[f];
        if (mn == 0.f && mc == 0.f) continue;
        const float x = s_xn[f];
        const float4 w  = *(const float4*)(w_num + f * DD + d4);
        const float4 bb = *(const float4*)(b_num + f * DD + d4);
        const float tx = fmaf(x,w.x,bb.x), ty = fmaf(x,w.y,bb.y), tz = fmaf(x,w.z,bb.z), tw = fmaf(x,w.w,bb.w);
        anx=fmaf(mn,tx,anx); any_=fmaf(mn,ty,any_); anz=fmaf(mn,tz,anz); anw=fmaf(mn,tw,anw);
        acx=fmaf(mc,tx,acx); acy=fmaf(mc,ty,acy); acz=fmaf(mc,tz,acz); acw=fmaf(mc,tw,acw);
    }
    for (int f = 0; f < NCAT; ++f) {
        const float mn = s_mn[NNUM+f], mc = s_mc[NNUM+f];
        if (mn == 0.f && mc == 0.f) continue;
        const int row = s_xc[f] + f * CARD;
        const float4 e  = *(const float4*)(emb_cat + row * DD + d4);
        const float4 bc = *(const float4*)(b_cat + f * DD + d4);
        const float tx=e.x+bc.x, ty=e.y+bc.y, tz=e.z+bc.z, tw=e.w+bc.w;
        anx=fmaf(mn,tx,anx); any_=fmaf(mn,ty,any_); anz=fmaf(mn,tz,anz); anw=fmaf(mn,tw,anw);
        acx=fmaf(mc,tx,acx); acy=fmaf(mc,ty,acy); acz=fmaf(mc,tz,acz); acw=fmaf(mc,tw,acw);
    }
    s_pn[d4+0]=anx*inv_n; s_pn[d4+1]=any_*inv_n; s_pn[d4+2]=anz*inv_n; s_pn[d4+3]=anw*inv_n;
    s_pc[d4+0]=acx*inv_c; s_pc[d4+1]=acy*inv_c; s_pc[d4+2]=acz*inv_c; s_pc[d4+3]=acw*inv_c;
    __syncthreads();
    const int wave = tid >> 6, lane = tid & 63;
    float pc[8];
    #pragma unroll
    for (int k = 0; k < 8; ++k) pc[k] = s_pc[lane * 8 + k];
    if (wave == 0) {
        const int idx = pred_idx_num[b];
        const float* wv = dec_num_W + idx * DD + lane * 8;
        float v = 0.f;
        #pragma unroll
        for (int k = 0; k < 8; ++k) v = fmaf(s_pn[lane*8+k], wv[k], v);
        #pragma unroll
        for (int off = 32; off > 0; off >>= 1) v += __shfl_down(v, off);
        if (lane == 0) out[b] = v + dec_num_b[idx];
    }
    const int e = pred_idx_cat[b] - NNUM;
    const float* baseW = dec_cat_W + (size_t)e * CARD * DD;
    const float* baseb = dec_cat_b + e * CARD;
    float* outc = out + BB + (size_t)b * CARD;
    for (int c = wave; c < CARD; c += 2) {
        const float* wv = baseW + c * DD + lane * 8;
        float v = 0.f;
        #pragma unroll
        for (int k = 0; k < 8; ++k) v = fmaf(pc[k], wv[k], v);
        #pragma unroll
        for (int off = 32; off > 0; off >>= 1) v += __shfl_down(v, off);
        if (lane == 0) outc[c] = v + baseb[c];
    }
}

extern "C" void kernel_launch(void* const* d_in, const int* in_sizes, int n_in,
                              void* d_out, int out_size, void* d_ws, size_t ws_size,
                              hipStream_t stream) {
    const float* x_num        = (const float*)d_in[0];
    const int*   x_cat        = (const int*)  d_in[1];
    const float* mask_num     = (const float*)d_in[2];
    const float* mask_cat     = (const float*)d_in[3];
    const int*   pred_idx_num = (const int*)  d_in[4];
    const int*   pred_idx_cat = (const int*)  d_in[5];
    const float* w_num        = (const float*)d_in[6];
    const float* b_num        = (const float*)d_in[7];
    const float* emb_cat      = (const float*)d_in[8];
    const float* b_cat        = (const float*)d_in[9];
    const float* dec_num_W    = (const float*)d_in[10];
    const float* dec_num_b    = (const float*)d_in[11];
    const float* dec_cat_W    = (const float*)d_in[12];
    const float* dec_cat_b    = (const float*)d_in[13];
    float* out = (float*)d_out;

    if (ws_size >= WS_NEEDED) {
        float* pooled = (float*)d_ws;
        int*   cnt    = (int*)((char*)d_ws + WS_CNT_OFF);
        int*   list   = (int*)((char*)d_ws + WS_LIST_OFF);

        pool_kernel<<<1 + BB / 4, 512, 0, stream>>>(
            x_num, x_cat, mask_num, mask_cat, pred_idx_num, pred_idx_cat,
            w_num, b_num, emb_cat, b_cat, dec_num_W, dec_num_b,
            cnt, list, pooled, out);
        cat_head<<<dim3(64, 2, 4), 256, 0, stream>>>(
            pooled, cnt, list, dec_cat_W, dec_cat_b, out);
    } else {
        rtdl_fused<<<BB, 128, 0, stream>>>(
            x_num, x_cat, mask_num, mask_cat, pred_idx_num, pred_idx_cat,
            w_num, b_num, emb_cat, b_cat, dec_num_W, dec_num_b,
            dec_cat_W, dec_cat_b, out);
    }
}

// Round 9
// 165.629 us; speedup vs baseline: 1.2044x; 1.2044x over previous
//
#include <hip/hip_runtime.h>

#define BB    4096
#define NNUM  64
#define NCAT  64
#define CARD  100
#define DD    512
#define FF    128

// workspace layout (9.44 MB — proven to fit)
#define WS_POOLED_BYTES ((size_t)BB * DD * 4)            // 8 MB
#define WS_CNT_OFF      WS_POOLED_BYTES
#define WS_LIST_OFF     (WS_CNT_OFF + 256)
#define WS_NEEDED       (WS_LIST_OFF + (size_t)64 * BB * 4)

// ---------------- kernel Pool v9: R6 structure + fg-parity phase stagger ----
// 1025 blocks x 512 threads. Block 0 = expert sorter. Blocks 1..1024 own rows
// [(blk-1)*4, +4). fg = tid>>7 owns features fg*16..+16; tl = tid&127 owns d4.
// SCHEDULE: fg 0,2 run numeric->cat; fg 1,3 run cat->numeric. At any instant
// each CU holds both FMA-heavy and gather-heavy waves -> cross-wave latency
// hiding (m114) instead of an all-wave gather burst.
// HARD RULES (measured): (512,4) -> 64-VGPR cap (R5: spill at >64);
// VGPR>64 halves occupancy (R7); keep >=4 independent gathers in flight
// per thread (R8: MLP loss = +32 us). This version: loops identical to R6,
// only their order is wave-uniformly swapped -> same registers.
__global__ __launch_bounds__(512, 4) void pool_kernel(
    const float* __restrict__ x_num, const int* __restrict__ x_cat,
    const float* __restrict__ mask_num, const float* __restrict__ mask_cat,
    const int* __restrict__ pred_idx_num, const int* __restrict__ pred_idx_cat,
    const float* __restrict__ w_num, const float* __restrict__ b_num,
    const float* __restrict__ emb_cat, const float* __restrict__ b_cat,
    const float* __restrict__ dec_num_W, const float* __restrict__ dec_num_b,
    int* __restrict__ cnt, int* __restrict__ list,
    float* __restrict__ pooled_cat,   // ws (B,512)
    float* __restrict__ out)          // out[0..B) = pred_num
{
    const int blk = blockIdx.x;
    const int tid = threadIdx.x;

    __shared__ float s_mn[4][FF];          // 2 KB
    __shared__ float s_mc[4][FF];          // 2 KB
    __shared__ float s_x[4][NNUM];         // 1 KB
    __shared__ int   s_idx[4][NCAT];       // 1 KB
    __shared__ float s_msum[2][4];
    __shared__ float s_red[2][2][4][DD];   // 32 KB (slot, type, row, d)

    // ---- block 0: expert counting-scatter (replaces memset + atomic binning) ----
    if (blk == 0) {
        int* s_hist = (int*)&s_mn[0][0];   // reuse LDS
        if (tid < 64) s_hist[tid] = 0;
        __syncthreads();
        for (int i = tid; i < BB; i += 512) {
            const int e = pred_idx_cat[i] - NNUM;
            const int pos = atomicAdd(&s_hist[e], 1);   // LDS atomic
            list[e * BB + pos] = i;
        }
        __syncthreads();
        if (tid < 64) cnt[tid] = s_hist[tid];
        return;
    }

    const int tl  = tid & 127;
    const int fg  = tid >> 7;          // 0..3
    const int d4  = tl * 4;
    const int rowbase = (blk - 1) * 4;

    // ---- stage row data (perfectly coalesced) ----
    ((float*)s_mn)[tid] = mask_num[rowbase * FF + tid];
    ((float*)s_mc)[tid] = mask_cat[rowbase * FF + tid];
    if (tid < 256) ((float*)s_x)[tid]       = x_num[rowbase * NNUM + tid];
    else           ((int*)s_idx)[tid - 256] = x_cat[rowbase * NCAT + (tid - 256)];
    __syncthreads();

    // mask sums (8 threads; consumed after later syncs)
    if (tid < 8) {
        const int r  = tid >> 1;
        const int ty = tid & 1;
        const float* m = ty ? s_mc[r] : s_mn[r];
        float s = 0.f;
        #pragma unroll 8
        for (int f2 = 0; f2 < FF; ++f2) s += m[f2];
        s_msum[ty][r] = s;
    }

    float accN[4][4] = {{0.f}};
    float accC[4][4] = {{0.f}};
    const int fbase = fg * 16;

    // ---- the two phase loops (identical bodies to R6) ----
    #define NUM_LOOP                                                            \
        _Pragma("unroll 2")                                                     \
        for (int fi = 0; fi < 16; ++fi) {                                       \
            const int f = fbase + fi;                                           \
            const float4 w  = *(const float4*)(w_num + f * DD + d4);            \
            const float4 bb = *(const float4*)(b_num + f * DD + d4);            \
            _Pragma("unroll")                                                   \
            for (int r = 0; r < 4; ++r) {                                       \
                const float mn = s_mn[r][f];                                    \
                const float mc = s_mc[r][f];                                    \
                const float x  = s_x[r][f];                                     \
                const float tx = fmaf(x, w.x, bb.x);                            \
                const float ty = fmaf(x, w.y, bb.y);                            \
                const float tz = fmaf(x, w.z, bb.z);                            \
                const float tw = fmaf(x, w.w, bb.w);                            \
                accN[r][0] = fmaf(mn, tx, accN[r][0]);                          \
                accN[r][1] = fmaf(mn, ty, accN[r][1]);                          \
                accN[r][2] = fmaf(mn, tz, accN[r][2]);                          \
                accN[r][3] = fmaf(mn, tw, accN[r][3]);                          \
                accC[r][0] = fmaf(mc, tx, accC[r][0]);                          \
                accC[r][1] = fmaf(mc, ty, accC[r][1]);                          \
                accC[r][2] = fmaf(mc, tz, accC[r][2]);                          \
                accC[r][3] = fmaf(mc, tw, accC[r][3]);                          \
            }                                                                   \
        }

    #define CAT_LOOP                                                            \
        _Pragma("unroll 2")                                                     \
        for (int fi = 0; fi < 16; ++fi) {                                       \
            const int f = fbase + fi;                                           \
            const float4 bc = *(const float4*)(b_cat + f * DD + d4);            \
            float4 ev[4];                                                       \
            _Pragma("unroll")                                                   \
            for (int r = 0; r < 4; ++r) {                                       \
                const float mn = s_mn[r][NNUM + f];                             \
                const float mc = s_mc[r][NNUM + f];                             \
                ev[r] = make_float4(0.f, 0.f, 0.f, 0.f);                        \
                if (mn != 0.f || mc != 0.f) {                                   \
                    const int card = s_idx[r][f];                               \
                    ev[r] = *(const float4*)(emb_cat +                          \
                              (size_t)(f * CARD + card) * DD + d4);             \
                }                                                               \
            }                                                                   \
            _Pragma("unroll")                                                   \
            for (int r = 0; r < 4; ++r) {                                       \
                const float mn = s_mn[r][NNUM + f];                             \
                const float mc = s_mc[r][NNUM + f];                             \
                const float tx = ev[r].x + bc.x;                                \
                const float ty = ev[r].y + bc.y;                                \
                const float tz = ev[r].z + bc.z;                                \
                const float tw = ev[r].w + bc.w;                                \
                accN[r][0] = fmaf(mn, tx, accN[r][0]);                          \
                accN[r][1] = fmaf(mn, ty, accN[r][1]);                          \
                accN[r][2] = fmaf(mn, tz, accN[r][2]);                          \
                accN[r][3] = fmaf(mn, tw, accN[r][3]);                          \
                accC[r][0] = fmaf(mc, tx, accC[r][0]);                          \
                accC[r][1] = fmaf(mc, ty, accC[r][1]);                          \
                accC[r][2] = fmaf(mc, tz, accC[r][2]);                          \
                accC[r][3] = fmaf(mc, tw, accC[r][3]);                          \
            }                                                                   \
        }

    // ---- phase stagger: odd fgs gather first, even fgs compute first ----
    if (fg & 1) {
        CAT_LOOP;
        NUM_LOOP;
    } else {
        NUM_LOOP;
        CAT_LOOP;
    }
    #undef NUM_LOOP
    #undef CAT_LOOP

    // ---- tree reduction over feature groups ----
    if (fg >= 2) {
        const int slot = fg - 2;
        #pragma unroll
        for (int r = 0; r < 4; ++r) {
            *(float4*)&s_red[slot][0][r][d4] = make_float4(accN[r][0], accN[r][1], accN[r][2], accN[r][3]);
            *(float4*)&s_red[slot][1][r][d4] = make_float4(accC[r][0], accC[r][1], accC[r][2], accC[r][3]);
        }
    }
    __syncthreads();
    if (fg < 2) {
        #pragma unroll
        for (int r = 0; r < 4; ++r) {
            const float4 vn = *(const float4*)&s_red[fg][0][r][d4];
            const float4 vc = *(const float4*)&s_red[fg][1][r][d4];
            accN[r][0] += vn.x; accN[r][1] += vn.y; accN[r][2] += vn.z; accN[r][3] += vn.w;
            accC[r][0] += vc.x; accC[r][1] += vc.y; accC[r][2] += vc.z; accC[r][3] += vc.w;
        }
    }
    __syncthreads();
    if (fg == 1) {
        #pragma unroll
        for (int r = 0; r < 4; ++r) {
            *(float4*)&s_red[0][0][r][d4] = make_float4(accN[r][0], accN[r][1], accN[r][2], accN[r][3]);
            *(float4*)&s_red[0][1][r][d4] = make_float4(accC[r][0], accC[r][1], accC[r][2], accC[r][3]);
        }
    }
    __syncthreads();

    float* s_pn = &s_red[1][0][0][0];      // reuse slot 1 as pooled_num staging [r*DD + d]
    if (fg == 0) {
        #pragma unroll
        for (int r = 0; r < 4; ++r) {
            const float4 vn = *(const float4*)&s_red[0][0][r][d4];
            const float4 vc = *(const float4*)&s_red[0][1][r][d4];
            const float invN = 1.f / s_msum[0][r];
            const float invC = 1.f / s_msum[1][r];
            float4 pc;
            pc.x = (accC[r][0] + vc.x) * invC; pc.y = (accC[r][1] + vc.y) * invC;
            pc.z = (accC[r][2] + vc.z) * invC; pc.w = (accC[r][3] + vc.w) * invC;
            *(float4*)(pooled_cat + (size_t)(rowbase + r) * DD + d4) = pc;
            float4 pn;
            pn.x = (accN[r][0] + vn.x) * invN; pn.y = (accN[r][1] + vn.y) * invN;
            pn.z = (accN[r][2] + vn.z) * invN; pn.w = (accN[r][3] + vn.w) * invN;
            *(float4*)(s_pn + r * DD + d4) = pn;
        }
    }
    __syncthreads();

    // ---- numeric head: waves 0..3 handle rows 0..3 ----
    const int wv   = tid >> 6;
    const int lane = tid & 63;
    if (wv < 4) {
        const int row = rowbase + wv;
        const int idx = pred_idx_num[row];
        const float* W = dec_num_W + (size_t)idx * DD + lane * 8;
        const float4 a0 = *(const float4*)(W);
        const float4 a1 = *(const float4*)(W + 4);
        const float4 p0 = *(const float4*)(s_pn + wv * DD + lane * 8);
        const float4 p1 = *(const float4*)(s_pn + wv * DD + lane * 8 + 4);
        float v = a0.x * p0.x + a0.y * p0.y + a0.z * p0.z + a0.w * p0.w
                + a1.x * p1.x + a1.y * p1.y + a1.z * p1.z + a1.w * p1.w;
        #pragma unroll
        for (int off = 32; off > 0; off >>= 1) v += __shfl_down(v, off);
        if (lane == 0) out[row] = v + dec_num_b[idx];
    }
}

// ---------------- kernel CatHead v3 (R3-proven): 32-row tiles, 256 threads ----
// grid (64 experts, 2 col-halves, 4 row-tile phases) x 256 threads.
// Each block: 32 rows x 50 cols, K=512 accumulated across 4 k-chunks in
// registers -> no atomics; bias fused into the store.
__global__ __launch_bounds__(256) void cat_head(
    const float* __restrict__ pooled_cat,
    const int* __restrict__ cnt, const int* __restrict__ list,
    const float* __restrict__ dec_cat_W, const float* __restrict__ dec_cat_b,
    float* __restrict__ out)
{
    const int e   = blockIdx.x;
    const int ch  = blockIdx.y;      // 0..1 (column half: 50 cards each)
    const int t   = blockIdx.z;      // 0..3 (row-tile phase, 32 rows each)
    const int tid = threadIdx.x;

    const int n = cnt[e];
    if (t * 32 >= n) return;         // empty tile -> exit (uniform)

    __shared__ float sW[8512];       // 50 cards x 128k, swizzled (34 KB)
    __shared__ float sP[32 * 132];   // 16.9 KB
    __shared__ int   s_rows[32];

    const int rg = tid >> 4;         // 0..15: 2 rows each
    const int cg = tid & 15;         // 0..15: 4 cols each (cl<50 valid)

    // per-thread column biases (uniform per block; loaded once)
    float bias[4];
    #pragma unroll
    for (int bq = 0; bq < 4; ++bq) {
        const int cl = cg * 4 + bq;
        bias[bq] = (cl < 50) ? dec_cat_b[e * CARD + ch * 50 + cl] : 0.f;
    }

    for (int rbase = t * 32; rbase < n; rbase += 128) {
        if (tid < 32) {
            const int ri = rbase + tid;
            s_rows[tid] = (ri < n) ? list[e * BB + ri] : -1;
        }

        float acc[2][4];
        #pragma unroll
        for (int a = 0; a < 2; ++a)
            #pragma unroll
            for (int bq = 0; bq < 4; ++bq) acc[a][bq] = 0.f;

        for (int dq = 0; dq < 4; ++dq) {
            __syncthreads();   // s_rows visible (dq==0) / prev compute done (dq>0)

            // stage W chunk: 50 cards x 128 k (swizzled to dodge bank conflicts)
            const float* Wb = dec_cat_W + ((size_t)e * CARD + ch * 50) * DD + dq * 128;
            for (int idx = tid; idx < 50 * 32; idx += 256) {
                const int c = idx >> 5;
                const int j = idx & 31;
                const float4 v = *(const float4*)(Wb + (size_t)c * DD + j * 4);
                *(float4*)(sW + c * 132 + (c >> 2) * 4 + j * 4) = v;
            }
            // stage P chunk: 32 rows x 128 k
            for (int idx = tid; idx < 32 * 32; idx += 256) {
                const int rl = idx >> 5;
                const int j  = idx & 31;
                const int row = s_rows[rl];
                float4 v = make_float4(0.f, 0.f, 0.f, 0.f);
                if (row >= 0)
                    v = *(const float4*)(pooled_cat + (size_t)row * DD + dq * 128 + j * 4);
                *(float4*)(sP + rl * 132 + j * 4) = v;
            }
            __syncthreads();

            #pragma unroll 4
            for (int k = 0; k < 32; ++k) {
                float4 p[2], w[4];
                #pragma unroll
                for (int a = 0; a < 2; ++a)
                    p[a] = *(const float4*)(sP + (rg * 2 + a) * 132 + k * 4);
                #pragma unroll
                for (int bq = 0; bq < 4; ++bq) {
                    const int cl = cg * 4 + bq;
                    w[bq] = *(const float4*)(sW + cl * 132 + (cl >> 2) * 4 + k * 4);
                }
                #pragma unroll
                for (int a = 0; a < 2; ++a)
                    #pragma unroll
                    for (int bq = 0; bq < 4; ++bq) {
                        acc[a][bq] = fmaf(p[a].x, w[bq].x, acc[a][bq]);
                        acc[a][bq] = fmaf(p[a].y, w[bq].y, acc[a][bq]);
                        acc[a][bq] = fmaf(p[a].z, w[bq].z, acc[a][bq]);
                        acc[a][bq] = fmaf(p[a].w, w[bq].w, acc[a][bq]);
                    }
            }
        }

        // direct store with fused bias (each output element owned by one thread)
        #pragma unroll
        for (int a = 0; a < 2; ++a) {
            const int row = s_rows[rg * 2 + a];
            if (row >= 0) {
                float* orow = out + BB + (size_t)row * CARD + ch * 50;
                #pragma unroll
                for (int bq = 0; bq < 4; ++bq) {
                    const int cl = cg * 4 + bq;
                    if (cl < 50) orow[cl] = acc[a][bq] + bias[bq];
                }
            }
        }
        __syncthreads();   // stores read s_rows; next iter overwrites it
    }
}

// ---------------- fallback: monolithic (used only if ws too small) ----------------
__global__ __launch_bounds__(128) void rtdl_fused(
    const float* __restrict__ x_num, const int* __restrict__ x_cat,
    const float* __restrict__ mask_num, const float* __restrict__ mask_cat,
    const int* __restrict__ pred_idx_num, const int* __restrict__ pred_idx_cat,
    const float* __restrict__ w_num, const float* __restrict__ b_num,
    const float* __restrict__ emb_cat, const float* __restrict__ b_cat,
    const float* __restrict__ dec_num_W, const float* __restrict__ dec_num_b,
    const float* __restrict__ dec_cat_W, const float* __restrict__ dec_cat_b,
    float* __restrict__ out)
{
    const int b   = blockIdx.x;
    const int tid = threadIdx.x;
    __shared__ float s_mn[FF];
    __shared__ float s_mc[FF];
    __shared__ float s_xn[NNUM];
    __shared__ int   s_xc[NCAT];
    __shared__ float s_pn[DD];
    __shared__ float s_pc[DD];
    s_mn[tid] = mask_num[b * FF + tid];
    s_mc[tid] = mask_cat[b * FF + tid];
    if (tid < NNUM) { s_xn[tid] = x_num[b * NNUM + tid]; s_xc[tid] = x_cat[b * NCAT + tid]; }
    __syncthreads();
    float sn = 0.f, sc = 0.f;
    for (int f = 0; f < FF; ++f) { sn += s_mn[f]; sc += s_mc[f]; }
    const float inv_n = 1.f / sn, inv_c = 1.f / sc;
    const int d4 = tid * 4;
    float anx=0,any_=0,anz=0,anw=0,acx=0,acy=0,acz=0,acw=0;
    for (int f = 0; f < NNUM; ++f) {
        const float mn = s_mn[f], mc = s_mc[f];
        if (mn == 0.f && mc == 0.f) continue;
        const float x = s_xn[f];
        const float4 w  = *(const float4*)(w_num + f * DD + d4);
        const float4 bb = *(const float4*)(b_num + f * DD + d4);
        const float tx = fmaf(x,w.x,bb.x), ty = fmaf(x,w.y,bb.y), tz = fmaf(x,w.z,bb.z), tw = fmaf(x,w.w,bb.w);
        anx=fmaf(mn,tx,anx); any_=fmaf(mn,ty,any_); anz=fmaf(mn,tz,anz); anw=fmaf(mn,tw,anw);
        acx=fmaf(mc,tx,acx); acy=fmaf(mc,ty,acy); acz=fmaf(mc,tz,acz); acw=fmaf(mc,tw,acw);
    }
    for (int f = 0; f < NCAT; ++f) {
        const float mn = s_mn[NNUM+f], mc = s_mc[NNUM+f];
        if (mn == 0.f && mc == 0.f) continue;
        const int row = s_xc[f] + f * CARD;
        const float4 e  = *(const float4*)(emb_cat + row * DD + d4);
        const float4 bc = *(const float4*)(b_cat + f * DD + d4);
        const float tx=e.x+bc.x, ty=e.y+bc.y, tz=e.z+bc.z, tw=e.w+bc.w;
        anx=fmaf(mn,tx,anx); any_=fmaf(mn,ty,any_); anz=fmaf(mn,tz,anz); anw=fmaf(mn,tw,anw);
        acx=fmaf(mc,tx,acx); acy=fmaf(mc,ty,acy); acz=fmaf(mc,tz,acz); acw=fmaf(mc,tw,acw);
    }
    s_pn[d4+0]=anx*inv_n; s_pn[d4+1]=any_*inv_n; s_pn[d4+2]=anz*inv_n; s_pn[d4+3]=anw*inv_n;
    s_pc[d4+0]=acx*inv_c; s_pc[d4+1]=acy*inv_c; s_pc[d4+2]=acz*inv_c; s_pc[d4+3]=acw*inv_c;
    __syncthreads();
    const int wave = tid >> 6, lane = tid & 63;
    float pc[8];
    #pragma unroll
    for (int k = 0; k < 8; ++k) pc[k] = s_pc[lane * 8 + k];
    if (wave == 0) {
        const int idx = pred_idx_num[b];
        const float* wv = dec_num_W + idx * DD + lane * 8;
        float v = 0.f;
        #pragma unroll
        for (int k = 0; k < 8; ++k) v = fmaf(s_pn[lane*8+k], wv[k], v);
        #pragma unroll
        for (int off = 32; off > 0; off >>= 1) v += __shfl_down(v, off);
        if (lane == 0) out[b] = v + dec_num_b[idx];
    }
    const int e = pred_idx_cat[b] - NNUM;
    const float* baseW = dec_cat_W + (size_t)e * CARD * DD;
    const float* baseb = dec_cat_b + e * CARD;
    float* outc = out + BB + (size_t)b * CARD;
    for (int c = wave; c < CARD; c += 2) {
        const float* wv = baseW + c * DD + lane * 8;
        float v = 0.f;
        #pragma unroll
        for (int k = 0; k < 8; ++k) v = fmaf(pc[k], wv[k], v);
        #pragma unroll
        for (int off = 32; off > 0; off >>= 1) v += __shfl_down(v, off);
        if (lane == 0) outc[c] = v + baseb[c];
    }
}

extern "C" void kernel_launch(void* const* d_in, const int* in_sizes, int n_in,
                              void* d_out, int out_size, void* d_ws, size_t ws_size,
                              hipStream_t stream) {
    const float* x_num        = (const float*)d_in[0];
    const int*   x_cat        = (const int*)  d_in[1];
    const float* mask_num     = (const float*)d_in[2];
    const float* mask_cat     = (const float*)d_in[3];
    const int*   pred_idx_num = (const int*)  d_in[4];
    const int*   pred_idx_cat = (const int*)  d_in[5];
    const float* w_num        = (const float*)d_in[6];
    const float* b_num        = (const float*)d_in[7];
    const float* emb_cat      = (const float*)d_in[8];
    const float* b_cat        = (const float*)d_in[9];
    const float* dec_num_W    = (const float*)d_in[10];
    const float* dec_num_b    = (const float*)d_in[11];
    const float* dec_cat_W    = (const float*)d_in[12];
    const float* dec_cat_b    = (const float*)d_in[13];
    float* out = (float*)d_out;

    if (ws_size >= WS_NEEDED) {
        float* pooled = (float*)d_ws;
        int*   cnt    = (int*)((char*)d_ws + WS_CNT_OFF);
        int*   list   = (int*)((char*)d_ws + WS_LIST_OFF);

        pool_kernel<<<1 + BB / 4, 512, 0, stream>>>(
            x_num, x_cat, mask_num, mask_cat, pred_idx_num, pred_idx_cat,
            w_num, b_num, emb_cat, b_cat, dec_num_W, dec_num_b,
            cnt, list, pooled, out);
        cat_head<<<dim3(64, 2, 4), 256, 0, stream>>>(
            pooled, cnt, list, dec_cat_W, dec_cat_b, out);
    } else {
        rtdl_fused<<<BB, 128, 0, stream>>>(
            x_num, x_cat, mask_num, mask_cat, pred_idx_num, pred_idx_cat,
            w_num, b_num, emb_cat, b_cat, dec_num_W, dec_num_b,
            dec_cat_W, dec_cat_b, out);
    }
}